// Round 1
// 311.282 us; speedup vs baseline: 2.0136x; 2.0136x over previous
//
#include <hip/hip_runtime.h>
#include <math.h>

#define BB 8
#define CC 256
#define KK 19
#define HW 16384
#define HW4 4096            // HW / 4 (float4 units)

// ---- K1: thread-per-channel contraction, map chunk staged in LDS ----
// One block per (b, hw-chunk). 256 threads <-> 256 channels, so each thread
// holds only acc[19] (spill-proof; round-1/2's acc[4][19]=76 spilled to
// scratch at VGPR_Count=64 -> the mystery 1.3 GB WRITE_SIZE).
//
// Round 4: the 5M global fp32 atomicAdds in the finalize were the dominant
// cost (WRITE_SIZE 223 MB on a kernel that legitimately writes 152 KB; all
// pipes <10% busy -> atomic-serialization-bound). Replaced with non-atomic
// per-block partial stores [bI][k][c] (k-major -> each of the 19 stores is a
// fully coalesced wave store) + a small K1b reduction kernel. Atomic path
// kept as a fallback when ws_size can't hold the 19.9 MB partial buffer.
#define CHUNK4 32           // float4 per chunk = 128 floats
#define NS (HW4 / CHUNK4)   // 128 chunks per batch

// Macro-unrolled k loops: guarantees literal acc indices -> SROA -> registers.
#define FOR_K(OP) OP(0) OP(1) OP(2) OP(3) OP(4) OP(5) OP(6) OP(7) OP(8) OP(9) \
                  OP(10) OP(11) OP(12) OP(13) OP(14) OP(15) OP(16) OP(17) OP(18)

__global__ __launch_bounds__(256, 4) void CGM_k1_contract(
    const float* __restrict__ feature,
    const float* __restrict__ map_,
    float* __restrict__ att,        // [BB*CC*KK] floats, pre-zeroed (fallback path)
    float* __restrict__ part)       // [grid][KK][CC] partials, or nullptr -> atomic path
{
    const int bI = blockIdx.x;      // b*NS + s
    const int s  = bI & (NS - 1);
    const int b  = bI >> 7;         // NS == 128
    const int c  = threadIdx.x;     // this thread's channel

    __shared__ float4 mlds[KK * CHUNK4];   // 9728 B

    // Stage map chunk: 19 rows x 32 float4, coalesced (512 B runs per row).
    const float4* m4 = (const float4*)map_ + (size_t)b * KK * HW4 + s * CHUNK4;
    for (int idx = threadIdx.x; idx < KK * CHUNK4; idx += 256) {
        const int k = idx >> 5;
        const int j = idx & 31;
        mlds[idx] = m4[(size_t)k * HW4 + j];
    }
    __syncthreads();

    float acc[KK];
#define ZERO(K) acc[K] = 0.f;
    FOR_K(ZERO)
#undef ZERO

    // Thread reads its own channel row: 32 float4 in 4 line-groups of 128 B,
    // each group loaded with 8 back-to-back dwordx4 so the line is consumed hot.
    const float4* f4 = (const float4*)feature
                     + (size_t)(b * CC + c) * HW4 + s * CHUNK4;

    for (int g = 0; g < 4; ++g) {
        float4 f[8];
#pragma unroll
        for (int u = 0; u < 8; ++u) f[u] = f4[g * 8 + u];
#pragma unroll
        for (int u = 0; u < 8; ++u) {
            const int i = g * 8 + u;
            const float4 fv = f[u];
            // LDS reads are same-address across all 64 lanes -> broadcast, free.
#define STEP(K) { const float4 m = mlds[(K) * CHUNK4 + i]; \
                  acc[K] += fv.x * m.x + fv.y * m.y + fv.z * m.z + fv.w * m.w; }
            FOR_K(STEP)
#undef STEP
        }
    }

    if (part) {
        // Split path: plain stores, k-major so each k is a coalesced wave store
        // (lanes c contiguous -> 256 B runs). 19.9 MB total = ~3 us of writes.
        float* dst = part + (size_t)bI * (KK * CC) + c;
#define FIN(K) dst[(K) * CC] = acc[K];
        FOR_K(FIN)
#undef FIN
    } else {
        // Fallback: fp32 atomics into the 152 KB att buffer (round-3 behavior).
        float* dst = att + (size_t)(b * CC + c) * KK;
#define FIN(K) atomicAdd(&dst[K], acc[K]);
        FOR_K(FIN)
#undef FIN
    }
}

// ---- K1b: fold the NS=128 hw-chunk partials into att. ----
// Grid = BB*KK = 152 blocks, 256 threads = channels. Loads are coalesced
// across lanes (256 consecutive floats per (bI,k) row); 19.9 MB read total.
__global__ __launch_bounds__(256) void CGM_k1b_reduce(
    const float* __restrict__ part,
    float* __restrict__ att)
{
    const int bk = blockIdx.x;      // b*KK + k
    const int b  = bk / KK;
    const int k  = bk - b * KK;
    const int c  = threadIdx.x;

    const float* p = part + ((size_t)(b * NS) * KK + k) * CC + c;
    float s0 = 0.f, s1 = 0.f, s2 = 0.f, s3 = 0.f;
#pragma unroll 4
    for (int s = 0; s < NS; s += 4) {
        s0 += p[(size_t)(s + 0) * KK * CC];
        s1 += p[(size_t)(s + 1) * KK * CC];
        s2 += p[(size_t)(s + 2) * KK * CC];
        s3 += p[(size_t)(s + 3) * KK * CC];
    }
    att[(size_t)(b * CC + c) * KK + k] = (s0 + s1) + (s2 + s3);
}

// ---- K2: gate + apply (round-2 structure, measured ~6.9 TB/s) ----
#define S2 8                 // hw splits
#define CT2 16               // channels per block
#define CHUNK24 (HW4 / S2)   // 512 float4

__global__ __launch_bounds__(256) void CGM_k2_apply(
    const float* __restrict__ feature,
    const float* __restrict__ gamma,
    const float* __restrict__ att,
    float* __restrict__ out)
{
    const int bI = blockIdx.x;
    const int ct = bI & 15;
    const int s  = (bI >> 4) & (S2 - 1);
    const int b  = bI >> 7;
    const int t  = threadIdx.x;
    const int c0 = ct * CT2;

    __shared__ float sgk[CT2 * KK];
    __shared__ float scale[CT2];

    // NOTE: CT2*KK = 304 > 256 threads — MUST be a strided loop, not `if`.
    // (Round 3's `if (t < 304)` left sgk[256..303] uninitialized -> absmax 58.)
    for (int idx = t; idx < CT2 * KK; idx += 256) {
        const int c = idx / KK;
        const int k = idx - c * KK;
        const float a = att[(size_t)(b * CC + c0 + c) * KK + k];
        const float sig = 1.f / (1.f + __expf(-a));
        sgk[idx] = sig * gamma[k];
    }
    __syncthreads();

    if (t < CT2) {
        float ssum = 0.f;
#define ADDK(K) ssum += sgk[t * KK + (K)];
        FOR_K(ADDK)
#undef ADDK
        scale[t] = 1.f + ssum;
    }
    __syncthreads();

    const float4* f4 = (const float4*)feature + (size_t)(b * CC + c0) * HW4;
    float4*       o4 = (float4*)out           + (size_t)(b * CC + c0) * HW4;
    const int ibase = s * CHUNK24;
#pragma unroll
    for (int c = 0; c < CT2; ++c) {
        const float sc = scale[c];
#pragma unroll
        for (int r = 0; r < CHUNK24 / 256; ++r) {   // 2 iterations
            const int i = ibase + r * 256 + t;
            const float4 f = f4[(size_t)c * HW4 + i];
            float4 o;
            o.x = f.x * sc;
            o.y = f.y * sc;
            o.z = f.z * sc;
            o.w = f.w * sc;
            o4[(size_t)c * HW4 + i] = o;
        }
    }
}

extern "C" void kernel_launch(void* const* d_in, const int* in_sizes, int n_in,
                              void* d_out, int out_size, void* d_ws, size_t ws_size,
                              hipStream_t stream) {
    const float* feature = (const float*)d_in[0];
    const float* map_    = (const float*)d_in[1];
    const float* gamma   = (const float*)d_in[2];
    float* out           = (float*)d_out;
    float* att           = (float*)d_ws;   // BB*CC*KK*4 = 155,648 B

    const size_t att_bytes  = (size_t)BB * CC * KK * sizeof(float);
    const size_t part_off   = (att_bytes + 255) & ~(size_t)255;
    const size_t part_bytes = (size_t)BB * NS * KK * CC * sizeof(float); // 19,922,944 B
    const bool   split      = ws_size >= part_off + part_bytes;
    float* part = split ? (float*)((char*)d_ws + part_off) : nullptr;

    if (!split) {
        // att buffer is re-poisoned to 0xAA before every launch — atomic
        // fallback needs it zeroed (hipMemsetAsync on stream is capture-safe).
        hipMemsetAsync(att, 0, att_bytes, stream);
    }

    const int grid1 = BB * NS;                // 1024
    CGM_k1_contract<<<grid1, 256, 0, stream>>>(feature, map_, att, part);

    if (split) {
        CGM_k1b_reduce<<<BB * KK, 256, 0, stream>>>(part, att);
    }

    const int grid2 = BB * S2 * (CC / CT2);   // 1024
    CGM_k2_apply<<<grid2, 256, 0, stream>>>(feature, gamma, att, out);
}